// Round 2
// baseline (13524.454 us; speedup 1.0000x reference)
//
#include <hip/hip_runtime.h>
#include <stdint.h>

#define BB   4
#define CC   4
#define HHH  512
#define WWW  512
#define HW   (HHH*WWW)        /* 262144 = 2^18 */
#define NIMG (BB*CC)          /* 16 */
#define NSRC 2
#define NLVL 5
#define KTOP 64
#define LDSH 4096             /* LDS sub-histogram bins (sizes 1..4096) */

// ---------------- union-find (min-root == min pixel index, matches reference) ----
// Correctness note: unite()'s convergence test uses ONLY atomic return values
// (coherent device-scope); path-halving plain stores are an optimization and
// always write a valid ancestor, so stale cross-XCD reads are benign.

__device__ __forceinline__ int findRoot(int* L, int i) {
  int p = L[i];
  while (p != i) {
    int gp = L[p];
    L[i] = gp;          // path halving; benign race (see note above)
    i = gp;
    p = L[i];
  }
  return i;
}

__device__ __forceinline__ void unite(int* L, int a, int b) {
  bool done = false;
  do {
    a = findRoot(L, a);
    b = findRoot(L, b);
    if (a < b) {
      int old = atomicMin(&L[b], a);
      done = (old == b);
      b = old;
    } else if (b < a) {
      int old = atomicMin(&L[a], b);
      done = (old == a);
      a = old;
    } else {
      done = true;
    }
  } while (!done);
}

// ---------------- masks ----------------

// base one-hot masks: out layout [src(2)][img(16)][HW], src0 = argmax(pred), src1 = target
__global__ void k_base_mask(const float* __restrict__ pred, const int* __restrict__ tgt,
                            uint8_t* __restrict__ mask) {
  int i = blockIdx.x * blockDim.x + threadIdx.x;   // over BB*HW
  if (i >= BB * HW) return;
  int b  = i >> 18;
  int hw = i & (HW - 1);
  float p0 = pred[(b * CC + 0) * HW + hw];
  float p1 = pred[(b * CC + 1) * HW + hw];
  float p2 = pred[(b * CC + 2) * HW + hw];
  float p3 = pred[(b * CC + 3) * HW + hw];
  int amax = 0; float best = p0;
  if (p1 > best) { best = p1; amax = 1; }
  if (p2 > best) { best = p2; amax = 2; }
  if (p3 > best) { best = p3; amax = 3; }
  int t = tgt[i];
  uint8_t* mp = mask;                         // src 0 (predictions)
  uint8_t* mt = mask + (size_t)NIMG * HW;     // src 1 (targets)
#pragma unroll
  for (int c = 0; c < CC; ++c) {
    mp[((size_t)(b * CC + c) << 18) + hw] = (uint8_t)(c == amax);
    mt[((size_t)(b * CC + c) << 18) + hw] = (uint8_t)(c == t);
  }
}

// 3x3 box morphology with zero padding. erode: all 9 in-window (borders can't pass).
__global__ void k_morph(const uint8_t* __restrict__ in, uint8_t* __restrict__ out, int erode) {
  int i = blockIdx.x * blockDim.x + threadIdx.x;   // over NSRC*NIMG*HW
  if (i >= NSRC * NIMG * HW) return;
  int hw = i & (HW - 1);
  int base = i - hw;
  int h = hw >> 9, w = hw & (WWW - 1);
  int s = 0;
#pragma unroll
  for (int dh = -1; dh <= 1; ++dh) {
#pragma unroll
    for (int dw = -1; dw <= 1; ++dw) {
      int hh = h + dh, ww = w + dw;
      if (hh >= 0 && hh < HHH && ww >= 0 && ww < WWW)
        s += in[base + (hh << 9) + ww];
    }
  }
  out[i] = erode ? (uint8_t)(s == 9) : (uint8_t)(s > 0);
}

// ---------------- CCL ----------------

__global__ void k_ccl_init(int* __restrict__ labels) {
  int i = blockIdx.x * blockDim.x + threadIdx.x;   // over NIMG*HW
  if (i >= NIMG * HW) return;
  labels[i] = i & (HW - 1);                        // local index within image
}

__global__ void k_ccl_merge(const uint8_t* __restrict__ m, int* __restrict__ labels) {
  int i = blockIdx.x * blockDim.x + threadIdx.x;
  if (i >= NIMG * HW) return;
  if (!m[i]) return;
  int p = i & (HW - 1);
  int* L = labels + (i - p);
  int w = p & (WWW - 1);
  if (w < WWW - 1 && m[i + 1])   unite(L, p, p + 1);
  if (p < HW - WWW && m[i + WWW]) unite(L, p, p + WWW);
}

// RACE-FIX: read-only traversal + single store to OWN entry. Previous version
// did path-halving writes here, so another thread's halving store could land
// after our final root store, leaving a non-root label -> fragmented counts.
__global__ void k_ccl_flatten(const uint8_t* __restrict__ m, int* __restrict__ labels) {
  int i = blockIdx.x * blockDim.x + threadIdx.x;
  if (i >= NIMG * HW) return;
  if (!m[i]) return;
  int p = i & (HW - 1);
  int* L = labels + (i - p);
  int r = p;
  int q = L[r];
  while (q != r) { r = q; q = L[r]; }   // reads only; others write only their own entry
  L[p] = r;
}

// 4 consecutive pixels per thread; run-aggregate equal roots before atomics
__global__ void k_ccl_count(const uint8_t* __restrict__ m, const int* __restrict__ labels,
                            int* __restrict__ counts) {
  int t = blockIdx.x * blockDim.x + threadIdx.x;   // over NIMG*HW/4
  int g = t * 4;
  if (g >= NIMG * HW) return;
  int imgbase = g & ~(HW - 1);
  int cur = -1, cn = 0;
#pragma unroll
  for (int j = 0; j < 4; ++j) {
    int gg = g + j;
    if (m[gg]) {
      int r = labels[gg];                          // exact local root after fixed flatten
      if (r == cur) { cn++; }
      else {
        if (cn > 0) atomicAdd(&counts[imgbase + cur], cn);
        cur = r; cn = 1;
      }
    }
  }
  if (cn > 0) atomicAdd(&counts[imgbase + cur], cn);
}

// histogram of component sizes; LDS sub-hist for small sizes (the common case)
__global__ void k_ccl_hist(const int* __restrict__ counts, int* __restrict__ hist) {
  __shared__ int lh[LDSH];
  int t = threadIdx.x;                             // 1024 threads
  for (int b = t; b < LDSH; b += 1024) lh[b] = 0;
  __syncthreads();
  int base = blockIdx.x * 16384;                   // 16 blocks per image (HW/16384)
  int img = base >> 18;
  int* gh = hist + ((size_t)img << 18);
#pragma unroll
  for (int j = 0; j < 16; ++j) {
    int i = base + t + j * 1024;
    int s = counts[i];
    if (s > 0) {
      if (s <= LDSH) atomicAdd(&lh[s - 1], 1);
      else           atomicAdd(&gh[s - 1], 1);
    }
  }
  __syncthreads();
  for (int b = t; b < LDSH; b += 1024)
    if (lh[b]) atomicAdd(&gh[b], lh[b]);
}

// sorted top-64 sizes from the per-image histogram (descending suffix walk)
__global__ void k_top64(const int* __restrict__ hist, float* __restrict__ top) {
  __shared__ int sc[1024];
  int img = blockIdx.x;
  const int* hh = hist + ((size_t)img << 18);
  int t = threadIdx.x;                             // 1024 threads
  int shi = HW - t * 256;                          // this thread covers sizes (shi-256, shi]
  int c = 0;
#pragma unroll 8
  for (int k = 0; k < 256; ++k) c += hh[shi - 1 - k];
  sc[t] = c;
  __syncthreads();
  for (int off = 1; off < 1024; off <<= 1) {       // Hillis-Steele inclusive scan
    int v = (t >= off) ? sc[t - off] : 0;
    __syncthreads();
    sc[t] += v;
    __syncthreads();
  }
  int pos = sc[t] - c;                             // # components with size > shi
  float* tp = top + (size_t)img * KTOP;
  if (t < KTOP) tp[t] = 0.f;
  __syncthreads();
  if (pos < KTOP && c > 0) {
    for (int k = 0; k < 256 && pos < KTOP; ++k) {
      int s = shi - k;
      int hc = hh[s - 1];
      while (hc-- > 0 && pos < KTOP) tp[pos++] = (float)s;
    }
  }
}

// loss[b] = sum over {lvl, c, k} |topP - topT| ; top layout [src][lvl][img][KTOP]
__global__ void k_loss(const float* __restrict__ top, float* __restrict__ out) {
  int b = blockIdx.x;
  int t = threadIdx.x;                             // 256
  float acc = 0.f;
  const int TOT = NLVL * CC * KTOP;                // 1280
  for (int e = t; e < TOT; e += 256) {
    int k = e & (KTOP - 1);
    int rest = e >> 6;
    int c = rest & (CC - 1);
    int lvl = rest >> 2;
    int img = b * CC + c;
    size_t iP = ((size_t)(0 * NLVL + lvl) * NIMG + img) * KTOP + k;
    size_t iT = ((size_t)(1 * NLVL + lvl) * NIMG + img) * KTOP + k;
    acc += fabsf(top[iP] - top[iT]);
  }
  __shared__ float r[256];
  r[t] = acc;
  __syncthreads();
  for (int off = 128; off > 0; off >>= 1) {
    if (t < off) r[t] += r[t + off];
    __syncthreads();
  }
  if (t == 0) out[b] = r[0];
}

// ---------------- driver ----------------

static inline void run_rounds(const uint8_t* maskbuf, int lvl, int* labels, int* counts,
                              int* hist, float* top, hipStream_t stream) {
  const int N = NIMG * HW;
  for (int src = 0; src < NSRC; ++src) {
    const uint8_t* m = maskbuf + (size_t)src * NIMG * HW;
    hipMemsetAsync(counts, 0, (size_t)N * 4, stream);
    hipMemsetAsync(hist,   0, (size_t)N * 4, stream);
    k_ccl_init   <<<N / 256, 256, 0, stream>>>(labels);
    k_ccl_merge  <<<N / 256, 256, 0, stream>>>(m, labels);
    k_ccl_flatten<<<N / 256, 256, 0, stream>>>(m, labels);
    k_ccl_count  <<<N / 4 / 256, 256, 0, stream>>>(m, labels, counts);
    k_ccl_hist   <<<N / 16384, 1024, 0, stream>>>(counts, hist);
    k_top64      <<<NIMG, 1024, 0, stream>>>(hist, top + (size_t)(src * NLVL + lvl) * NIMG * KTOP);
  }
}

extern "C" void kernel_launch(void* const* d_in, const int* in_sizes, int n_in,
                              void* d_out, int out_size, void* d_ws, size_t ws_size,
                              hipStream_t stream) {
  const float* pred = (const float*)d_in[0];
  const int*   tgt  = (const int*)d_in[1];
  float* out = (float*)d_out;

  uint8_t* ws = (uint8_t*)d_ws;
  size_t off = 0;
  uint8_t* mbase = ws + off; off += (size_t)NSRC * NIMG * HW;      // 8 MB, level 2
  uint8_t* mA    = ws + off; off += (size_t)NSRC * NIMG * HW;      // 8 MB
  uint8_t* mB    = ws + off; off += (size_t)NSRC * NIMG * HW;      // 8 MB
  int* labels = (int*)(ws + off); off += (size_t)NIMG * HW * 4;    // 16 MB
  int* counts = (int*)(ws + off); off += (size_t)NIMG * HW * 4;    // 16 MB
  int* hist   = (int*)(ws + off); off += (size_t)NIMG * HW * 4;    // 16 MB
  float* top  = (float*)(ws + off); off += (size_t)NSRC * NLVL * NIMG * KTOP * 4;

  const int MN = NSRC * NIMG * HW;   // morphology thread count (8M)

  // base one-hot masks (level 2)
  k_base_mask<<<(BB * HW) / 256, 256, 0, stream>>>(pred, tgt, mbase);
  run_rounds(mbase, 2, labels, counts, hist, top, stream);

  // erosion chain: level 3, 4
  k_morph<<<MN / 256, 256, 0, stream>>>(mbase, mA, 1);
  run_rounds(mA, 3, labels, counts, hist, top, stream);
  k_morph<<<MN / 256, 256, 0, stream>>>(mA, mB, 1);
  run_rounds(mB, 4, labels, counts, hist, top, stream);

  // dilation chain: level 1, 0
  k_morph<<<MN / 256, 256, 0, stream>>>(mbase, mA, 0);
  run_rounds(mA, 1, labels, counts, hist, top, stream);
  k_morph<<<MN / 256, 256, 0, stream>>>(mA, mB, 0);
  run_rounds(mB, 0, labels, counts, hist, top, stream);

  k_loss<<<BB, 256, 0, stream>>>(top, out);
}

// Round 3
// 2909.747 us; speedup vs baseline: 4.6480x; 4.6480x over previous
//
#include <hip/hip_runtime.h>
#include <stdint.h>

#define BB   4
#define CC   4
#define HHH  512
#define WWW  512
#define HW   (HHH*WWW)        /* 262144 = 2^18 */
#define NIMG (BB*CC)          /* 16 */
#define NSRC 2
#define NLVL 5
#define KTOP 64
#define LDSH 4096             /* LDS sub-histogram bins (sizes 1..4096) */

// ---------------- union-find (min-root == min pixel index, matches reference) ----
// unite()'s convergence test uses ONLY atomic return values; path-halving plain
// stores always write a valid ancestor (chain values are monotone decreasing),
// so overwrites never break connectivity.

__device__ __forceinline__ int findRoot(int* L, int i) {
  int p = L[i];
  while (p != i) {
    int gp = L[p];
    L[i] = gp;          // path halving; benign race (see note above)
    i = gp;
    p = L[i];
  }
  return i;
}

__device__ __forceinline__ void unite(int* L, int a, int b) {
  bool done = false;
  do {
    a = findRoot(L, a);
    b = findRoot(L, b);
    if (a < b) {
      int old = atomicMin(&L[b], a);
      done = (old == b);
      b = old;
    } else if (b < a) {
      int old = atomicMin(&L[a], b);
      done = (old == a);
      a = old;
    } else {
      done = true;
    }
  } while (!done);
}

// ---------------- masks ----------------

// base one-hot masks: out layout [src(2)][img(16)][HW], src0 = argmax(pred), src1 = target
__global__ void k_base_mask(const float* __restrict__ pred, const int* __restrict__ tgt,
                            uint8_t* __restrict__ mask) {
  int i = blockIdx.x * blockDim.x + threadIdx.x;   // over BB*HW
  if (i >= BB * HW) return;
  int b  = i >> 18;
  int hw = i & (HW - 1);
  float p0 = pred[(b * CC + 0) * HW + hw];
  float p1 = pred[(b * CC + 1) * HW + hw];
  float p2 = pred[(b * CC + 2) * HW + hw];
  float p3 = pred[(b * CC + 3) * HW + hw];
  int amax = 0; float best = p0;
  if (p1 > best) { best = p1; amax = 1; }
  if (p2 > best) { best = p2; amax = 2; }
  if (p3 > best) { best = p3; amax = 3; }
  int t = tgt[i];
  uint8_t* mp = mask;                         // src 0 (predictions)
  uint8_t* mt = mask + (size_t)NIMG * HW;     // src 1 (targets)
#pragma unroll
  for (int c = 0; c < CC; ++c) {
    mp[((size_t)(b * CC + c) << 18) + hw] = (uint8_t)(c == amax);
    mt[((size_t)(b * CC + c) << 18) + hw] = (uint8_t)(c == t);
  }
}

// 3x3 box morphology with zero padding. erode: all 9 in-window (borders can't pass).
__global__ void k_morph(const uint8_t* __restrict__ in, uint8_t* __restrict__ out, int erode) {
  int i = blockIdx.x * blockDim.x + threadIdx.x;   // over NSRC*NIMG*HW
  if (i >= NSRC * NIMG * HW) return;
  int hw = i & (HW - 1);
  int base = i - hw;
  int h = hw >> 9, w = hw & (WWW - 1);
  int s = 0;
#pragma unroll
  for (int dh = -1; dh <= 1; ++dh) {
#pragma unroll
    for (int dw = -1; dw <= 1; ++dw) {
      int hh = h + dh, ww = w + dw;
      if (hh >= 0 && hh < HHH && ww >= 0 && ww < WWW)
        s += in[base + (hh << 9) + ww];
    }
  }
  out[i] = erode ? (uint8_t)(s == 9) : (uint8_t)(s > 0);
}

// ---------------- CCL ----------------

// Run-based init: fg pixel label = start of its horizontal run within the
// 64-px wave segment (ballot, zero atomics). bg labels never read -> no init.
// Also folds the counts/hist zeroing (removes 2 memset dispatches per round).
__global__ void k_run_init(const uint8_t* __restrict__ m, int* __restrict__ labels,
                           int* __restrict__ counts, int* __restrict__ hist) {
  int g = blockIdx.x * blockDim.x + threadIdx.x;   // over NIMG*HW
  if (g >= NIMG * HW) return;
  counts[g] = 0;
  hist[g] = 0;
  bool fg = m[g] != 0;
  unsigned long long fb = __ballot(fg);
  int lane = threadIdx.x & 63;                     // == g & 63 (block=256, W=512)
  if (fg) {
    unsigned long long lowz = ~fb & ((lane == 0) ? 0ull : ((1ull << lane) - 1));
    int z = lowz ? (63 - __clzll(lowz)) : -1;      // last bg lane below me
    int hw = g & (HW - 1);
    labels[g] = hw - lane + (z + 1);               // run start (local index)
  }
}

// Sparse merge: (a) horizontal unite only across 64-px segment boundaries,
// (b) vertical unite only where not implied by left neighbors (skip rule:
// if m[p-1] && m[p-W-1] the connection p~p-W is implied by column w-1).
__global__ void k_merge_sparse(const uint8_t* __restrict__ m, int* __restrict__ labels) {
  int g = blockIdx.x * blockDim.x + threadIdx.x;
  if (g >= NIMG * HW) return;
  if (!m[g]) return;
  int hw = g & (HW - 1);
  int* L = labels + (g - hw);
  int w = hw & (WWW - 1);
  int lane = hw & 63;
  if (lane == 0 && w > 0 && m[g - 1])
    unite(L, hw, hw - 1);                          // cross-segment horizontal
  if (hw >= WWW && m[g - WWW]) {
    bool skip = (w > 0) && m[g - 1] && m[g - WWW - 1];
    if (!skip) unite(L, hw, hw - WWW);             // vertical
  }
}

// Head-dedup flatten: only run-head lanes walk the chain (read-only), root is
// broadcast to the rest of the run via shfl. Each thread stores ONLY its own
// entry -> final labels are exact roots (no halving-store clobber race).
__global__ void k_ccl_flatten(const uint8_t* __restrict__ m, int* __restrict__ labels) {
  int g = blockIdx.x * blockDim.x + threadIdx.x;
  if (g >= NIMG * HW) return;
  int lane = threadIdx.x & 63;
  bool fg = m[g] != 0;
  int hw = g & (HW - 1);
  int* L = labels + (g - hw);
  int l0 = fg ? L[hw] : -1;
  int lp = __shfl_up(l0, 1);
  bool head = fg && (lane == 0 || l0 != lp);
  int root = 0;
  if (head) {
    int r = l0;
    int q = L[r];
    while (q != r) { r = q; q = L[r]; }            // reads only
    root = r;
  }
  unsigned long long hb = __ballot(head);
  unsigned long long lemask = (lane == 63) ? ~0ull : ((2ull << lane) - 1);
  unsigned long long below = hb & lemask;
  int hlane = below ? (63 - __clzll(below)) : 0;   // nearest head <= my lane
  int rb = __shfl(root, hlane);
  if (fg) L[hw] = rb;
}

// Wave-segmented count: one atomicAdd per run per wave (head lane adds the
// run's lane-count). ~64x fewer same-address atomics than per-pixel.
__global__ void k_ccl_count(const uint8_t* __restrict__ m, const int* __restrict__ labels,
                            int* __restrict__ counts) {
  int g = blockIdx.x * blockDim.x + threadIdx.x;
  if (g >= NIMG * HW) return;
  int lane = threadIdx.x & 63;
  bool fg = m[g] != 0;
  int r = fg ? labels[g] : -1;
  int rp = __shfl_up(r, 1);
  bool head = fg && (lane == 0 || r != rp);
  unsigned long long hb = __ballot(head);
  unsigned long long fb = __ballot(fg);
  if (head) {
    unsigned long long higher = (lane == 63) ? 0ull : (hb >> (lane + 1));
    int next = higher ? (lane + 1 + (__ffsll(higher) - 1)) : 64;
    unsigned long long upmask = ~((lane == 0) ? 0ull : ((1ull << lane) - 1));
    unsigned long long rangemask = ((next >= 64) ? ~0ull : ((1ull << next) - 1)) & upmask;
    int len = __popcll(fb & rangemask);            // fg lanes in [lane, next) == my run
    atomicAdd(&counts[(g & ~(HW - 1)) + r], len);
  }
}

// histogram of component sizes; LDS sub-hist for small sizes (the common case)
__global__ void k_ccl_hist(const int* __restrict__ counts, int* __restrict__ hist) {
  __shared__ int lh[LDSH];
  int t = threadIdx.x;                             // 1024 threads
  for (int b = t; b < LDSH; b += 1024) lh[b] = 0;
  __syncthreads();
  int base = blockIdx.x * 16384;                   // 16 blocks per image (HW/16384)
  int img = base >> 18;
  int* gh = hist + ((size_t)img << 18);
#pragma unroll
  for (int j = 0; j < 16; ++j) {
    int i = base + t + j * 1024;
    int s = counts[i];
    if (s > 0) {
      if (s <= LDSH) atomicAdd(&lh[s - 1], 1);
      else           atomicAdd(&gh[s - 1], 1);
    }
  }
  __syncthreads();
  for (int b = t; b < LDSH; b += 1024)
    if (lh[b]) atomicAdd(&gh[b], lh[b]);
}

// sorted top-64 sizes from the per-image histogram (descending suffix walk)
__global__ void k_top64(const int* __restrict__ hist, float* __restrict__ top) {
  __shared__ int sc[1024];
  int img = blockIdx.x;
  const int* hh = hist + ((size_t)img << 18);
  int t = threadIdx.x;                             // 1024 threads
  int slo = HW - (t + 1) * 256;                    // this thread covers sizes (slo, slo+256]
  const int4* h4 = (const int4*)(hh + slo);
  int c = 0;
#pragma unroll 16
  for (int k = 0; k < 64; ++k) {
    int4 v = h4[k];
    c += v.x + v.y + v.z + v.w;
  }
  sc[t] = c;
  __syncthreads();
  for (int off = 1; off < 1024; off <<= 1) {       // Hillis-Steele inclusive scan
    int v = (t >= off) ? sc[t - off] : 0;
    __syncthreads();
    sc[t] += v;
    __syncthreads();
  }
  int pos = sc[t] - c;                             // # components with size > slo+256
  float* tp = top + (size_t)img * KTOP;
  if (t < KTOP) tp[t] = 0.f;
  __syncthreads();
  if (pos < KTOP && c > 0) {
    int shi = slo + 256;
    for (int k = 0; k < 256 && pos < KTOP; ++k) {
      int s = shi - k;
      int hc = hh[s - 1];
      while (hc-- > 0 && pos < KTOP) tp[pos++] = (float)s;
    }
  }
}

// loss[b] = sum over {lvl, c, k} |topP - topT| ; top layout [src][lvl][img][KTOP]
__global__ void k_loss(const float* __restrict__ top, float* __restrict__ out) {
  int b = blockIdx.x;
  int t = threadIdx.x;                             // 256
  float acc = 0.f;
  const int TOT = NLVL * CC * KTOP;                // 1280
  for (int e = t; e < TOT; e += 256) {
    int k = e & (KTOP - 1);
    int rest = e >> 6;
    int c = rest & (CC - 1);
    int lvl = rest >> 2;
    int img = b * CC + c;
    size_t iP = ((size_t)(0 * NLVL + lvl) * NIMG + img) * KTOP + k;
    size_t iT = ((size_t)(1 * NLVL + lvl) * NIMG + img) * KTOP + k;
    acc += fabsf(top[iP] - top[iT]);
  }
  __shared__ float r[256];
  r[t] = acc;
  __syncthreads();
  for (int off = 128; off > 0; off >>= 1) {
    if (t < off) r[t] += r[t + off];
    __syncthreads();
  }
  if (t == 0) out[b] = r[0];
}

// ---------------- driver ----------------

static inline void run_rounds(const uint8_t* maskbuf, int lvl, int* labels, int* counts,
                              int* hist, float* top, hipStream_t stream) {
  const int N = NIMG * HW;
  for (int src = 0; src < NSRC; ++src) {
    const uint8_t* m = maskbuf + (size_t)src * NIMG * HW;
    k_run_init    <<<N / 256, 256, 0, stream>>>(m, labels, counts, hist);
    k_merge_sparse<<<N / 256, 256, 0, stream>>>(m, labels);
    k_ccl_flatten <<<N / 256, 256, 0, stream>>>(m, labels);
    k_ccl_count   <<<N / 256, 256, 0, stream>>>(m, labels, counts);
    k_ccl_hist    <<<N / 16384, 1024, 0, stream>>>(counts, hist);
    k_top64       <<<NIMG, 1024, 0, stream>>>(hist, top + (size_t)(src * NLVL + lvl) * NIMG * KTOP);
  }
}

extern "C" void kernel_launch(void* const* d_in, const int* in_sizes, int n_in,
                              void* d_out, int out_size, void* d_ws, size_t ws_size,
                              hipStream_t stream) {
  const float* pred = (const float*)d_in[0];
  const int*   tgt  = (const int*)d_in[1];
  float* out = (float*)d_out;

  uint8_t* ws = (uint8_t*)d_ws;
  size_t off = 0;
  uint8_t* mbase = ws + off; off += (size_t)NSRC * NIMG * HW;      // 8 MB, level 2
  uint8_t* mA    = ws + off; off += (size_t)NSRC * NIMG * HW;      // 8 MB
  uint8_t* mB    = ws + off; off += (size_t)NSRC * NIMG * HW;      // 8 MB
  int* labels = (int*)(ws + off); off += (size_t)NIMG * HW * 4;    // 16 MB
  int* counts = (int*)(ws + off); off += (size_t)NIMG * HW * 4;    // 16 MB
  int* hist   = (int*)(ws + off); off += (size_t)NIMG * HW * 4;    // 16 MB
  float* top  = (float*)(ws + off); off += (size_t)NSRC * NLVL * NIMG * KTOP * 4;

  const int MN = NSRC * NIMG * HW;   // morphology thread count (8M)

  // base one-hot masks (level 2)
  k_base_mask<<<(BB * HW) / 256, 256, 0, stream>>>(pred, tgt, mbase);
  run_rounds(mbase, 2, labels, counts, hist, top, stream);

  // erosion chain: level 3, 4
  k_morph<<<MN / 256, 256, 0, stream>>>(mbase, mA, 1);
  run_rounds(mA, 3, labels, counts, hist, top, stream);
  k_morph<<<MN / 256, 256, 0, stream>>>(mA, mB, 1);
  run_rounds(mB, 4, labels, counts, hist, top, stream);

  // dilation chain: level 1, 0
  k_morph<<<MN / 256, 256, 0, stream>>>(mbase, mA, 0);
  run_rounds(mA, 1, labels, counts, hist, top, stream);
  k_morph<<<MN / 256, 256, 0, stream>>>(mA, mB, 0);
  run_rounds(mB, 0, labels, counts, hist, top, stream);

  k_loss<<<BB, 256, 0, stream>>>(top, out);
}

// Round 4
// 1124.987 us; speedup vs baseline: 12.0219x; 2.5865x over previous
//
#include <hip/hip_runtime.h>
#include <stdint.h>

#define BB   4
#define CC   4
#define HHH  512
#define WWW  512
#define HW   (HHH*WWW)        /* 262144 = 2^18 */
#define NIMG (BB*CC)          /* 16 */
#define NSRC 2
#define NLVL 5
#define KTOP 64
#define NBIN 4096             /* histogram bins; sizes > NBIN go to the large list (<=63 of them) */
#define HSZ  512              /* LDS root-dedup hash (max distinct roots per 1024-px block = 512) */

// ---------------- union-find (min-root == min pixel index, matches reference) ----
// unite()'s convergence test uses ONLY atomic return values; path-halving plain
// stores always write a valid ancestor (chain values are monotone decreasing),
// so overwrites never break connectivity.

__device__ __forceinline__ int findRoot(int* L, int i) {
  int p = L[i];
  while (p != i) {
    int gp = L[p];
    L[i] = gp;          // path halving; benign race (see note above)
    i = gp;
    p = L[i];
  }
  return i;
}

__device__ __forceinline__ void unite(int* L, int a, int b) {
  bool done = false;
  do {
    a = findRoot(L, a);
    b = findRoot(L, b);
    if (a < b) {
      int old = atomicMin(&L[b], a);
      done = (old == b);
      b = old;
    } else if (b < a) {
      int old = atomicMin(&L[a], b);
      done = (old == a);
      a = old;
    } else {
      done = true;
    }
  } while (!done);
}

// ---------------- masks ----------------

// base one-hot masks: out layout [src(2)][img(16)][HW], src0 = argmax(pred), src1 = target
__global__ void k_base_mask(const float* __restrict__ pred, const int* __restrict__ tgt,
                            uint8_t* __restrict__ mask) {
  int i = blockIdx.x * blockDim.x + threadIdx.x;   // over BB*HW
  if (i >= BB * HW) return;
  int b  = i >> 18;
  int hw = i & (HW - 1);
  float p0 = pred[(b * CC + 0) * HW + hw];
  float p1 = pred[(b * CC + 1) * HW + hw];
  float p2 = pred[(b * CC + 2) * HW + hw];
  float p3 = pred[(b * CC + 3) * HW + hw];
  int amax = 0; float best = p0;
  if (p1 > best) { best = p1; amax = 1; }
  if (p2 > best) { best = p2; amax = 2; }
  if (p3 > best) { best = p3; amax = 3; }
  int t = tgt[i];
  uint8_t* mp = mask;                         // src 0 (predictions)
  uint8_t* mt = mask + (size_t)NIMG * HW;     // src 1 (targets)
#pragma unroll
  for (int c = 0; c < CC; ++c) {
    mp[((size_t)(b * CC + c) << 18) + hw] = (uint8_t)(c == amax);
    mt[((size_t)(b * CC + c) << 18) + hw] = (uint8_t)(c == t);
  }
}

// 3x3 box morphology with zero padding. erode: all 9 in-window (borders can't pass).
__global__ void k_morph(const uint8_t* __restrict__ in, uint8_t* __restrict__ out, int erode) {
  int i = blockIdx.x * blockDim.x + threadIdx.x;   // over NSRC*NIMG*HW
  if (i >= NSRC * NIMG * HW) return;
  int hw = i & (HW - 1);
  int base = i - hw;
  int h = hw >> 9, w = hw & (WWW - 1);
  int s = 0;
#pragma unroll
  for (int dh = -1; dh <= 1; ++dh) {
#pragma unroll
    for (int dw = -1; dw <= 1; ++dw) {
      int hh = h + dh, ww = w + dw;
      if (hh >= 0 && hh < HHH && ww >= 0 && ww < WWW)
        s += in[base + (hh << 9) + ww];
    }
  }
  out[i] = erode ? (uint8_t)(s == 9) : (uint8_t)(s > 0);
}

// ---------------- CCL ----------------

// Run-based init: fg pixel label = start of its horizontal run within the
// 64-px wave segment (ballot, zero atomics). bg labels never read -> no init.
// Also folds all per-round zeroing (counts, hist, lcount).
__global__ void k_run_init(const uint8_t* __restrict__ m, int* __restrict__ labels,
                           int* __restrict__ counts, int* __restrict__ hist,
                           int* __restrict__ lcount) {
  int g = blockIdx.x * blockDim.x + threadIdx.x;   // over NIMG*HW
  if (g >= NIMG * HW) return;
  counts[g] = 0;
  if (g < NIMG * NBIN) hist[g] = 0;
  if (g < NIMG) lcount[g] = 0;
  bool fg = m[g] != 0;
  unsigned long long fb = __ballot(fg);
  int lane = threadIdx.x & 63;                     // == g & 63 (block=256, W=512)
  if (fg) {
    unsigned long long lowz = ~fb & ((lane == 0) ? 0ull : ((1ull << lane) - 1));
    int z = lowz ? (63 - __clzll(lowz)) : -1;      // last bg lane below me
    int hw = g & (HW - 1);
    labels[g] = hw - lane + (z + 1);               // run start (local index)
  }
}

// Sparse merge: (a) horizontal unite only across 64-px segment boundaries,
// (b) vertical unite only where not implied by left neighbors (skip rule:
// if m[p-1] && m[p-W-1] the connection p~p-W is implied by column w-1).
__global__ void k_merge_sparse(const uint8_t* __restrict__ m, int* __restrict__ labels) {
  int g = blockIdx.x * blockDim.x + threadIdx.x;
  if (g >= NIMG * HW) return;
  if (!m[g]) return;
  int hw = g & (HW - 1);
  int* L = labels + (g - hw);
  int w = hw & (WWW - 1);
  int lane = hw & 63;
  if (lane == 0 && w > 0 && m[g - 1])
    unite(L, hw, hw - 1);                          // cross-segment horizontal
  if (hw >= WWW && m[g - WWW]) {
    bool skip = (w > 0) && m[g - 1] && m[g - WWW - 1];
    if (!skip) unite(L, hw, hw - WWW);             // vertical
  }
}

// Fused flatten+count: per-run head lanes walk the parent chain (read-only),
// compute run length via ballots, dedupe roots through an LDS hash, then one
// global atomic per distinct root per 1024-px block. labels is never written
// and counts sees ~256 same-address atomics/image instead of ~4096.
__global__ void k_flatten_count(const uint8_t* __restrict__ m, const int* __restrict__ labels,
                                int* __restrict__ counts) {
  __shared__ int hk[HSZ];
  __shared__ int hv[HSZ];
  int t = threadIdx.x;                             // 1024
  if (t < HSZ) { hk[t] = -1; hv[t] = 0; }
  __syncthreads();
  int g = blockIdx.x * 1024 + t;
  int lane = t & 63;
  bool fg = m[g] != 0;
  int hw = g & (HW - 1);
  const int* L = labels + (g - hw);
  int l0 = fg ? L[hw] : -1;
  int lp = __shfl_up(l0, 1);
  bool head = fg && (lane == 0 || l0 != lp);
  unsigned long long hb = __ballot(head);
  unsigned long long fb = __ballot(fg);
  if (head) {
    int r = l0;                                    // read-only root walk
    int q = L[r];
    while (q != r) { r = q; q = L[r]; }
    unsigned long long higher = (lane == 63) ? 0ull : (hb >> (lane + 1));
    int next = higher ? (lane + 1 + (__ffsll(higher) - 1)) : 64;
    unsigned long long upmask = ~((lane == 0) ? 0ull : ((1ull << lane) - 1));
    unsigned long long rangemask = ((next >= 64) ? ~0ull : ((1ull << next) - 1)) & upmask;
    int len = __popcll(fb & rangemask);            // fg lanes in [lane, next) == my run
    unsigned h = ((unsigned)r * 2654435761u >> 16) & (HSZ - 1);
    for (;;) {                                     // linear-probe insert (table can hold worst case)
      int prev = atomicCAS(&hk[h], -1, r);
      if (prev == -1 || prev == r) { atomicAdd(&hv[h], len); break; }
      h = (h + 1) & (HSZ - 1);
    }
  }
  __syncthreads();
  int imgbase = (blockIdx.x * 1024) & ~(HW - 1);   // blocks never straddle images
  if (t < HSZ && hk[t] != -1)
    atomicAdd(&counts[imgbase + hk[t]], hv[t]);
}

// histogram of sizes <= NBIN (LDS, then merged to a 4096-bin global hist);
// sizes > NBIN (at most 63 per image) appended to a compact per-image list.
__global__ void k_ccl_hist(const int* __restrict__ counts, int* __restrict__ hist,
                           int* __restrict__ lcount, int* __restrict__ lsizes) {
  __shared__ int lh[NBIN];
  int t = threadIdx.x;                             // 1024 threads
  for (int b = t; b < NBIN; b += 1024) lh[b] = 0;
  __syncthreads();
  int base = blockIdx.x * 16384;                   // 16 blocks per image (HW/16384)
  int img = base >> 18;
#pragma unroll
  for (int j = 0; j < 16; ++j) {
    int s = counts[base + t + j * 1024];
    if (s > 0) {
      if (s <= NBIN) atomicAdd(&lh[s - 1], 1);
      else {
        int idx = atomicAdd(&lcount[img], 1);
        if (idx < KTOP) lsizes[img * KTOP + idx] = s;
      }
    }
  }
  __syncthreads();
  int* gh = hist + img * NBIN;
  for (int b = t; b < NBIN; b += 1024)
    if (lh[b]) atomicAdd(&gh[b], lh[b]);
}

// sorted top-64: rank-sort the large list (all > NBIN), then suffix-walk the
// 4096-bin LDS-resident histogram to fill the remaining slots.
__global__ void k_top64(const int* __restrict__ hist, const int* __restrict__ lcount,
                        const int* __restrict__ lsizes, float* __restrict__ top) {
  __shared__ int lh[NBIN];
  __shared__ int ls[KTOP];
  __shared__ int sc[256];
  int img = blockIdx.x;
  int t = threadIdx.x;                             // 256
  const int* gh = hist + img * NBIN;
  for (int k = t; k < NBIN; k += 256) lh[k] = gh[k];
  int n = lcount[img];
  if (n > KTOP) n = KTOP;
  if (t < KTOP) ls[t] = (t < n) ? lsizes[img * KTOP + t] : 0;
  float* tp = top + (size_t)img * KTOP;
  if (t < KTOP) tp[t] = 0.f;
  __syncthreads();
  if (t < n) {                                     // rank-sort descending (n <= 63)
    int myv = ls[t], rank = 0;
    for (int j = 0; j < n; ++j) {
      int vj = ls[j];
      rank += (vj > myv) || (vj == myv && j < t);
    }
    tp[rank] = (float)myv;
  }
  // chunk sums, descending size order: thread t covers bins [NBIN-16(t+1), NBIN-16t)
  int base = NBIN - 16 * (t + 1);
  int c = 0;
#pragma unroll
  for (int k = 0; k < 16; ++k) c += lh[base + k];
  sc[t] = c;
  __syncthreads();
  for (int off = 1; off < 256; off <<= 1) {        // Hillis-Steele inclusive scan
    int v = (t >= off) ? sc[t - off] : 0;
    __syncthreads();
    sc[t] += v;
    __syncthreads();
  }
  int pos = n + sc[t] - c;                         // components ranked before my chunk
  if (pos < KTOP && c > 0) {
    for (int k = 15; k >= 0 && pos < KTOP; --k) {  // descending size within chunk
      int s = base + k + 1;
      int hc = lh[base + k];
      while (hc-- > 0 && pos < KTOP) tp[pos++] = (float)s;
    }
  }
}

// loss[b] = sum over {lvl, c, k} |topP - topT| ; top layout [src][lvl][img][KTOP]
__global__ void k_loss(const float* __restrict__ top, float* __restrict__ out) {
  int b = blockIdx.x;
  int t = threadIdx.x;                             // 256
  float acc = 0.f;
  const int TOT = NLVL * CC * KTOP;                // 1280
  for (int e = t; e < TOT; e += 256) {
    int k = e & (KTOP - 1);
    int rest = e >> 6;
    int c = rest & (CC - 1);
    int lvl = rest >> 2;
    int img = b * CC + c;
    size_t iP = ((size_t)(0 * NLVL + lvl) * NIMG + img) * KTOP + k;
    size_t iT = ((size_t)(1 * NLVL + lvl) * NIMG + img) * KTOP + k;
    acc += fabsf(top[iP] - top[iT]);
  }
  __shared__ float r[256];
  r[t] = acc;
  __syncthreads();
  for (int off = 128; off > 0; off >>= 1) {
    if (t < off) r[t] += r[t + off];
    __syncthreads();
  }
  if (t == 0) out[b] = r[0];
}

// ---------------- driver ----------------

static inline void run_rounds(const uint8_t* maskbuf, int lvl, int* labels, int* counts,
                              int* hist, int* lcount, int* lsizes, float* top,
                              hipStream_t stream) {
  const int N = NIMG * HW;
  for (int src = 0; src < NSRC; ++src) {
    const uint8_t* m = maskbuf + (size_t)src * NIMG * HW;
    k_run_init     <<<N / 256, 256, 0, stream>>>(m, labels, counts, hist, lcount);
    k_merge_sparse <<<N / 256, 256, 0, stream>>>(m, labels);
    k_flatten_count<<<N / 1024, 1024, 0, stream>>>(m, labels, counts);
    k_ccl_hist     <<<N / 16384, 1024, 0, stream>>>(counts, hist, lcount, lsizes);
    k_top64        <<<NIMG, 256, 0, stream>>>(hist, lcount, lsizes,
                                              top + (size_t)(src * NLVL + lvl) * NIMG * KTOP);
  }
}

extern "C" void kernel_launch(void* const* d_in, const int* in_sizes, int n_in,
                              void* d_out, int out_size, void* d_ws, size_t ws_size,
                              hipStream_t stream) {
  const float* pred = (const float*)d_in[0];
  const int*   tgt  = (const int*)d_in[1];
  float* out = (float*)d_out;

  uint8_t* ws = (uint8_t*)d_ws;
  size_t off = 0;
  uint8_t* mbase = ws + off; off += (size_t)NSRC * NIMG * HW;        // 8 MB, level 2
  uint8_t* mA    = ws + off; off += (size_t)NSRC * NIMG * HW;        // 8 MB
  uint8_t* mB    = ws + off; off += (size_t)NSRC * NIMG * HW;        // 8 MB
  int* labels = (int*)(ws + off); off += (size_t)NIMG * HW * 4;      // 16 MB
  int* counts = (int*)(ws + off); off += (size_t)NIMG * HW * 4;      // 16 MB
  int* hist   = (int*)(ws + off); off += (size_t)NIMG * NBIN * 4;    // 256 KB
  int* lcount = (int*)(ws + off); off += (size_t)NIMG * 4;
  int* lsizes = (int*)(ws + off); off += (size_t)NIMG * KTOP * 4;
  float* top  = (float*)(ws + off); off += (size_t)NSRC * NLVL * NIMG * KTOP * 4;

  const int MN = NSRC * NIMG * HW;   // morphology thread count (8M)

  // base one-hot masks (level 2)
  k_base_mask<<<(BB * HW) / 256, 256, 0, stream>>>(pred, tgt, mbase);
  run_rounds(mbase, 2, labels, counts, hist, lcount, lsizes, top, stream);

  // erosion chain: level 3, 4
  k_morph<<<MN / 256, 256, 0, stream>>>(mbase, mA, 1);
  run_rounds(mA, 3, labels, counts, hist, lcount, lsizes, top, stream);
  k_morph<<<MN / 256, 256, 0, stream>>>(mA, mB, 1);
  run_rounds(mB, 4, labels, counts, hist, lcount, lsizes, top, stream);

  // dilation chain: level 1, 0
  k_morph<<<MN / 256, 256, 0, stream>>>(mbase, mA, 0);
  run_rounds(mA, 1, labels, counts, hist, lcount, lsizes, top, stream);
  k_morph<<<MN / 256, 256, 0, stream>>>(mA, mB, 0);
  run_rounds(mB, 0, labels, counts, hist, lcount, lsizes, top, stream);

  k_loss<<<BB, 256, 0, stream>>>(top, out);
}

// Round 5
// 919.283 us; speedup vs baseline: 14.7120x; 1.2238x over previous
//
#include <hip/hip_runtime.h>
#include <stdint.h>

typedef unsigned long long u64;

#define BB   4
#define CC   4
#define HHH  512
#define WWW  512
#define HW   (HHH*WWW)        /* 262144 = 2^18 */
#define NIMG (BB*CC)          /* 16 */
#define NSRC 2
#define NLVL 5
#define KTOP 64
#define NBIN 4096             /* histogram bins; sizes > NBIN go to the large list (<=63 of them) */
#define HSZ  512              /* LDS root-dedup hash (max distinct roots per 1024-px block = 512) */
#define WPI  4096             /* 64-bit words per image (512 rows * 8) */

// ---------------- union-find (min-root == min pixel index) ----------------
// unite()'s convergence test uses ONLY atomic return values; path-halving plain
// stores always write a valid ancestor (chain values are monotone decreasing).

__device__ __forceinline__ int findRoot(int* L, int i) {
  int p = L[i];
  while (p != i) {
    int gp = L[p];
    L[i] = gp;          // path halving; benign race
    i = gp;
    p = L[i];
  }
  return i;
}

__device__ __forceinline__ void unite(int* L, int a, int b) {
  bool done = false;
  do {
    a = findRoot(L, a);
    b = findRoot(L, b);
    if (a < b) {
      int old = atomicMin(&L[b], a);
      done = (old == b);
      b = old;
    } else if (b < a) {
      int old = atomicMin(&L[a], b);
      done = (old == a);
      a = old;
    } else {
      done = true;
    }
  } while (!done);
}

// run start bit (within 64-px segment) for a pixel at bit k of word w
__device__ __forceinline__ int runstart_bit(u64 w, int k) {
  u64 lowz = ~w & ((k == 0) ? 0ull : ((1ull << k) - 1));
  return lowz ? (64 - __clzll(lowz)) : 0;   // highest zero below k, +1
}

// ---------------- masks (bitmaps: 1 bit/px, u64 words, [src][img][4096]) ----

__global__ void k_base_mask_bits(const float* __restrict__ pred, const int* __restrict__ tgt,
                                 u64* __restrict__ bm) {
  int i = blockIdx.x * blockDim.x + threadIdx.x;   // over BB*HW, waves = 64 consecutive px
  if (i >= BB * HW) return;
  int b  = i >> 18;
  int hw = i & (HW - 1);
  float p0 = pred[(b * CC + 0) * HW + hw];
  float p1 = pred[(b * CC + 1) * HW + hw];
  float p2 = pred[(b * CC + 2) * HW + hw];
  float p3 = pred[(b * CC + 3) * HW + hw];
  int amax = 0; float best = p0;
  if (p1 > best) { best = p1; amax = 1; }
  if (p2 > best) { best = p2; amax = 2; }
  if (p3 > best) { best = p3; amax = 3; }
  int tg = tgt[i];
  int lane = threadIdx.x & 63;
  u64* bp = bm;                         // src 0 (predictions)
  u64* bt = bm + (size_t)NIMG * WPI;    // src 1 (targets)
#pragma unroll
  for (int c = 0; c < CC; ++c) {
    u64 wp = __ballot(amax == c);
    u64 wt = __ballot(tg == c);
    if (lane == 0) {
      int wi = ((b * CC + c) << 12) + (hw >> 6);
      bp[wi] = wp;
      bt[wi] = wt;
    }
  }
}

// 3x3 box morphology on bitmaps, zero padding. One thread per output word.
__global__ void k_morph_bits(const u64* __restrict__ in, u64* __restrict__ out, int erode) {
  int t = blockIdx.x * blockDim.x + threadIdx.x;   // over NSRC*NIMG*WPI = 131072
  if (t >= NSRC * NIMG * WPI) return;
  int word = t & (WPI - 1);
  int row = word >> 3, wc = word & 7;
  const u64* ip = in + (t - word);                 // image base
  u64 c0 = ip[word];
  u64 cm = wc ? ip[word - 1] : 0;
  u64 cp = (wc < 7) ? ip[word + 1] : 0;
  u64 u0 = 0, um = 0, up_ = 0, d0 = 0, dm = 0, dp = 0;
  if (row) {
    u0 = ip[word - 8];
    um = wc ? ip[word - 9] : 0;
    up_ = (wc < 7) ? ip[word - 7] : 0;
  }
  if (row < HHH - 1) {
    d0 = ip[word + 8];
    dm = wc ? ip[word + 7] : 0;
    dp = (wc < 7) ? ip[word + 9] : 0;
  }
  u64 v, vm, vp, r;
  if (erode) {
    v = u0 & c0 & d0; vm = um & cm & dm; vp = up_ & cp & dp;
    r = v & ((v << 1) | (vm >> 63)) & ((v >> 1) | (vp << 63));
  } else {
    v = u0 | c0 | d0; vm = um | cm | dm; vp = up_ | cp | dp;
    r = v | (v << 1) | (vm >> 63) | (v >> 1) | (vp << 63);
  }
  out[t] = r;
}

// ---------------- CCL ----------------

// Sparse init: write labels ONLY at run-head nodes (label = own index).
__global__ void k_runinit_bits(const u64* __restrict__ bm, int* __restrict__ labels) {
  int t = blockIdx.x * blockDim.x + threadIdx.x;   // over NIMG*WPI = 65536
  if (t >= NIMG * WPI) return;
  u64 w = bm[t];
  if (!w) return;
  int word = t & (WPI - 1);
  int* L = labels + ((t >> 12) << 18);
  int segbase = ((word >> 3) << 9) + ((word & 7) << 6);
  u64 hm = w & ~(w << 1);                          // segment-fragmented run heads
  while (hm) {
    int k = __ffsll(hm) - 1; hm &= hm - 1;
    L[segbase + k] = segbase + k;
  }
}

// Word-sparse merge: horizontal unite across word boundaries; vertical unite
// where not implied by left column (need = r0 & up & ~(ls(r0) & ls(up))).
// Unite endpoints are run-start NODES computed from the bit patterns.
__global__ void k_merge_bits(const u64* __restrict__ bm, int* __restrict__ labels) {
  int t = blockIdx.x * blockDim.x + threadIdx.x;   // over NIMG*WPI
  if (t >= NIMG * WPI) return;
  u64 r0 = bm[t];
  if (!r0) return;
  int word = t & (WPI - 1);
  int row = word >> 3, wc = word & 7;
  int* L = labels + ((t >> 12) << 18);
  int segbase = (row << 9) + (wc << 6);
  u64 prev = wc ? bm[t - 1] : 0;
  if ((r0 & 1) && (prev >> 63))                    // cross-word horizontal
    unite(L, segbase, segbase - 64 + runstart_bit(prev, 63));
  if (row) {
    u64 up = bm[t - 8];
    if (up) {
      u64 upprev = wc ? bm[t - 9] : 0;
      u64 lsr0 = (r0 << 1) | (prev >> 63);
      u64 lsup = (up << 1) | (upprev >> 63);
      u64 need = r0 & up & ~(lsr0 & lsup);
      while (need) {
        int k = __ffsll(need) - 1; need &= need - 1;
        int a = segbase + runstart_bit(r0, k);
        int b = segbase - 512 + runstart_bit(up, k);
        unite(L, a, b);
      }
    }
  }
}

// Fused flatten+count: wave reads one broadcast word; head lanes (from bit
// pattern) walk the chain read-only, compute run length from bits, dedupe
// roots through an LDS hash, then one global atomic per distinct root/block.
__global__ void k_flatten_count(const u64* __restrict__ bm, const int* __restrict__ labels,
                                int* __restrict__ counts) {
  __shared__ int hk[HSZ];
  __shared__ int hv[HSZ];
  int t = threadIdx.x;                             // 1024
  if (t < HSZ) { hk[t] = -1; hv[t] = 0; }
  __syncthreads();
  int g = blockIdx.x * 1024 + t;                   // pixel id over NIMG*HW
  int lane = t & 63;
  u64 w = bm[g >> 6];                              // == img*WPI + word (broadcast)
  const int* L = labels + ((g >> 18) << 18);
  int hw = g & (HW - 1);
  u64 hm = w & ~(w << 1);
  if ((hm >> lane) & 1) {
    u64 inv = ~(w >> lane);
    int len = inv ? (__ffsll(inv) - 1) : (64 - lane);
    int r = hw;                                    // read-only root walk
    int q = L[r];
    while (q != r) { r = q; q = L[r]; }
    unsigned h = ((unsigned)r * 2654435761u >> 16) & (HSZ - 1);
    for (;;) {                                     // linear probe; table holds worst case
      int prevk = atomicCAS(&hk[h], -1, r);
      if (prevk == -1 || prevk == r) { atomicAdd(&hv[h], len); break; }
      h = (h + 1) & (HSZ - 1);
    }
  }
  __syncthreads();
  int imgbase = (blockIdx.x * 1024) & ~(HW - 1);   // blocks never straddle images
  if (t < HSZ && hk[t] != -1)
    atomicAdd(&counts[imgbase + hk[t]], hv[t]);
}

// histogram of sizes <= NBIN (LDS -> 4096-bin global hist);
// sizes > NBIN (at most 63 per image) appended to a compact per-image list.
__global__ void k_ccl_hist(const int* __restrict__ counts, int* __restrict__ hist,
                           int* __restrict__ lcount, int* __restrict__ lsizes) {
  __shared__ int lh[NBIN];
  int t = threadIdx.x;                             // 1024 threads
  for (int b = t; b < NBIN; b += 1024) lh[b] = 0;
  __syncthreads();
  int base = blockIdx.x * 16384;                   // 16 blocks per image
  int img = base >> 18;
#pragma unroll
  for (int j = 0; j < 16; ++j) {
    int s = counts[base + t + j * 1024];
    if (s > 0) {
      if (s <= NBIN) atomicAdd(&lh[s - 1], 1);
      else {
        int idx = atomicAdd(&lcount[img], 1);
        if (idx < KTOP) lsizes[img * KTOP + idx] = s;
      }
    }
  }
  __syncthreads();
  int* gh = hist + img * NBIN;
  for (int b = t; b < NBIN; b += 1024)
    if (lh[b]) atomicAdd(&gh[b], lh[b]);
}

// sorted top-64: rank-sort the large list (all > NBIN), then suffix-walk the
// 4096-bin LDS-resident histogram to fill the remaining slots.
__global__ void k_top64(const int* __restrict__ hist, const int* __restrict__ lcount,
                        const int* __restrict__ lsizes, float* __restrict__ top) {
  __shared__ int lh[NBIN];
  __shared__ int ls[KTOP];
  __shared__ int sc[256];
  int img = blockIdx.x;
  int t = threadIdx.x;                             // 256
  const int* gh = hist + img * NBIN;
  for (int k = t; k < NBIN; k += 256) lh[k] = gh[k];
  int n = lcount[img];
  if (n > KTOP) n = KTOP;
  if (t < KTOP) ls[t] = (t < n) ? lsizes[img * KTOP + t] : 0;
  float* tp = top + (size_t)img * KTOP;
  if (t < KTOP) tp[t] = 0.f;
  __syncthreads();
  if (t < n) {                                     // rank-sort descending (n <= 63)
    int myv = ls[t], rank = 0;
    for (int j = 0; j < n; ++j) {
      int vj = ls[j];
      rank += (vj > myv) || (vj == myv && j < t);
    }
    tp[rank] = (float)myv;
  }
  int base = NBIN - 16 * (t + 1);                  // descending chunks of 16 bins
  int c = 0;
#pragma unroll
  for (int k = 0; k < 16; ++k) c += lh[base + k];
  sc[t] = c;
  __syncthreads();
  for (int off = 1; off < 256; off <<= 1) {        // Hillis-Steele inclusive scan
    int v = (t >= off) ? sc[t - off] : 0;
    __syncthreads();
    sc[t] += v;
    __syncthreads();
  }
  int pos = n + sc[t] - c;                         // components ranked before my chunk
  if (pos < KTOP && c > 0) {
    for (int k = 15; k >= 0 && pos < KTOP; --k) {
      int s = base + k + 1;
      int hc = lh[base + k];
      while (hc-- > 0 && pos < KTOP) tp[pos++] = (float)s;
    }
  }
}

// loss[b] = sum over {lvl, c, k} |topP - topT| ; top layout [src][lvl][img][KTOP]
__global__ void k_loss(const float* __restrict__ top, float* __restrict__ out) {
  int b = blockIdx.x;
  int t = threadIdx.x;                             // 256
  float acc = 0.f;
  const int TOT = NLVL * CC * KTOP;                // 1280
  for (int e = t; e < TOT; e += 256) {
    int k = e & (KTOP - 1);
    int rest = e >> 6;
    int c = rest & (CC - 1);
    int lvl = rest >> 2;
    int img = b * CC + c;
    size_t iP = ((size_t)(0 * NLVL + lvl) * NIMG + img) * KTOP + k;
    size_t iT = ((size_t)(1 * NLVL + lvl) * NIMG + img) * KTOP + k;
    acc += fabsf(top[iP] - top[iT]);
  }
  __shared__ float r[256];
  r[t] = acc;
  __syncthreads();
  for (int off = 128; off > 0; off >>= 1) {
    if (t < off) r[t] += r[t + off];
    __syncthreads();
  }
  if (t == 0) out[b] = r[0];
}

// ---------------- driver ----------------

static inline void run_rounds(const u64* bmbuf, int lvl, int* labels, int* counts,
                              int* hist, int* lcount, int* lsizes, float* top,
                              size_t zero_bytes, hipStream_t stream) {
  const int NW = NIMG * WPI;                       // 65536 words per src
  for (int src = 0; src < NSRC; ++src) {
    const u64* m = bmbuf + (size_t)src * NW;
    hipMemsetAsync(counts, 0, zero_bytes, stream); // counts+hist+lcount (contiguous)
    k_runinit_bits <<<NW / 256, 256, 0, stream>>>(m, labels);
    k_merge_bits   <<<NW / 256, 256, 0, stream>>>(m, labels);
    k_flatten_count<<<NIMG * HW / 1024, 1024, 0, stream>>>(m, labels, counts);
    k_ccl_hist     <<<NIMG * HW / 16384, 1024, 0, stream>>>(counts, hist, lcount, lsizes);
    k_top64        <<<NIMG, 256, 0, stream>>>(hist, lcount, lsizes,
                                              top + (size_t)(src * NLVL + lvl) * NIMG * KTOP);
  }
}

extern "C" void kernel_launch(void* const* d_in, const int* in_sizes, int n_in,
                              void* d_out, int out_size, void* d_ws, size_t ws_size,
                              hipStream_t stream) {
  const float* pred = (const float*)d_in[0];
  const int*   tgt  = (const int*)d_in[1];
  float* out = (float*)d_out;

  uint8_t* ws = (uint8_t*)d_ws;
  size_t off = 0;
  u64* bmbase = (u64*)(ws + off); off += (size_t)NSRC * NIMG * WPI * 8;   // 1 MB, level 2
  u64* bmA    = (u64*)(ws + off); off += (size_t)NSRC * NIMG * WPI * 8;   // 1 MB
  u64* bmB    = (u64*)(ws + off); off += (size_t)NSRC * NIMG * WPI * 8;   // 1 MB
  int* labels = (int*)(ws + off); off += (size_t)NIMG * HW * 4;           // 16 MB
  int* counts = (int*)(ws + off); off += (size_t)NIMG * HW * 4;           // 16 MB
  int* hist   = (int*)(ws + off); off += (size_t)NIMG * NBIN * 4;         // 256 KB
  int* lcount = (int*)(ws + off); off += (size_t)NIMG * 4;
  int* lsizes = (int*)(ws + off); off += (size_t)NIMG * KTOP * 4;
  float* top  = (float*)(ws + off); off += (size_t)NSRC * NLVL * NIMG * KTOP * 4;
  const size_t zero_bytes = (size_t)NIMG * HW * 4 + (size_t)NIMG * NBIN * 4 + (size_t)NIMG * 4;

  const int MW = NSRC * NIMG * WPI;                // morphology words (131072)

  // base one-hot bitmaps (level 2)
  k_base_mask_bits<<<(BB * HW) / 256, 256, 0, stream>>>(pred, tgt, bmbase);
  run_rounds(bmbase, 2, labels, counts, hist, lcount, lsizes, top, zero_bytes, stream);

  // erosion chain: level 3, 4
  k_morph_bits<<<MW / 256, 256, 0, stream>>>(bmbase, bmA, 1);
  run_rounds(bmA, 3, labels, counts, hist, lcount, lsizes, top, zero_bytes, stream);
  k_morph_bits<<<MW / 256, 256, 0, stream>>>(bmA, bmB, 1);
  run_rounds(bmB, 4, labels, counts, hist, lcount, lsizes, top, zero_bytes, stream);

  // dilation chain: level 1, 0
  k_morph_bits<<<MW / 256, 256, 0, stream>>>(bmbase, bmA, 0);
  run_rounds(bmA, 1, labels, counts, hist, lcount, lsizes, top, zero_bytes, stream);
  k_morph_bits<<<MW / 256, 256, 0, stream>>>(bmA, bmB, 0);
  run_rounds(bmB, 0, labels, counts, hist, lcount, lsizes, top, zero_bytes, stream);

  k_loss<<<BB, 256, 0, stream>>>(top, out);
}